// Round 2
// baseline (502.654 us; speedup 1.0000x reference)
//
#include <hip/hip_runtime.h>
#include <stdint.h>

#define N_PIX    65536
#define C_DIM    720
#define K_CLS    19
#define M_PROTO  10
#define NPROTO   190
#define CPAD     768
#define OFF_Q    12451840
#define OFF_PRED 24903680

typedef _Float16 half8 __attribute__((ext_vector_type(8)));
typedef _Float16 h4    __attribute__((ext_vector_type(4)));
typedef float    f32x4 __attribute__((ext_vector_type(4)));

// ---- workspace layout (byte offsets) ----
#define WS_E       0u          // 192 floats
#define WS_G2      768u        // 192 floats
#define WS_G3      1536u       // 192 floats
#define WS_CNT     2304u       // 32 floats
#define WS_TIECNT  2432u       // 1 int
#define WS_PSCALE  4096u       // 65536 * float4
#define WS_EPIX    1052672u    // 65536*10 floats
#define WS_U       3674112u    // 65536 floats
#define WS_TIELIST 3936256u    // 65536 ints
#define WS_PF16    4198400u    // 192*768 half (pre-swizzled)
#define WS_PF32    4493312u    // 190*720 float
#define WS_XH      5046272u    // 65536*768 half (pre-swizzled), ends ~105.7 MB

// async 16B global->LDS copy (LDS dest must be wave-uniform base; HW adds lane*16)
__device__ __forceinline__ void async16(const void* g, void* l) {
    __builtin_amdgcn_global_load_lds(
        (const __attribute__((address_space(1))) unsigned int*)g,
        (__attribute__((address_space(3))) unsigned int*)l, 16, 0, 0);
}

// ------------------------------------------------------------------
__global__ void zero_acc(float* ws) {
    if (threadIdx.x < 640) ws[threadIdx.x] = 0.f;
}

// ------------------------------------------------------------------
// L2-normalize prototypes -> f16 padded+swizzled [192][768] and f32 [190][720]
// swizzle: halfword col c stored at ((c>>3)^(p&7))*8 + (c&7)
__global__ void proto_prep(const float* __restrict__ protos,
                           _Float16* __restrict__ pf16,
                           float* __restrict__ pf32) {
    int p = blockIdx.x;
    int tid = threadIdx.x;
    if (p >= NPROTO) {   // padding rows 190,191 -> zeros (all-zero: position irrelevant)
        for (int c = tid; c < CPAD; c += 256) pf16[(size_t)p * CPAD + c] = (_Float16)0.f;
        return;
    }
    __shared__ float red[256];
    const float* row = protos + (size_t)p * C_DIM;
    float ss = 0.f;
    for (int c = tid; c < C_DIM; c += 256) { float v = row[c]; ss += v * v; }
    red[tid] = ss;
    __syncthreads();
    for (int s = 128; s > 0; s >>= 1) {
        if (tid < s) red[tid] += red[tid + s];
        __syncthreads();
    }
    float invn = 1.f / fmaxf(sqrtf(red[0]), 1e-12f);
    int e8 = p & 7;
    for (int c = tid; c < CPAD; c += 256) {
        float v = (c < C_DIM) ? row[c] * invn : 0.f;
        int sw = (((c >> 3) ^ e8) << 3) | (c & 7);
        pf16[(size_t)p * CPAD + sw] = (_Float16)v;
        if (c < C_DIM) pf32[(size_t)p * C_DIM + c] = v;
    }
}

// ------------------------------------------------------------------
// LayerNorm+L2 stats, then write normalized f16 row (padded to 768, pre-swizzled).
// One wave per pixel row.
__global__ __launch_bounds__(256) void stats_xh(const float* __restrict__ x,
                                                const float* __restrict__ gamma,
                                                const float* __restrict__ beta,
                                                float4* __restrict__ pscale,
                                                _Float16* __restrict__ xh) {
    int wave = threadIdx.x >> 6, lane = threadIdx.x & 63;
    int n = blockIdx.x * 4 + wave;
    const float4* row4 = (const float4*)(x + (size_t)n * C_DIM);
    const float4* g4 = (const float4*)gamma;
    const float4* b4 = (const float4*)beta;

    float a[8];
    #pragma unroll
    for (int t = 0; t < 8; ++t) a[t] = 0.f;
    float4 xv[3], gv[3], bv[3];
    #pragma unroll
    for (int j = 0; j < 3; ++j) {
        int f = lane + 64 * j;
        float4 xvv = make_float4(0.f, 0.f, 0.f, 0.f), gvv = xvv, bvv = xvv;
        if (f < 180) { xvv = row4[f]; gvv = g4[f]; bvv = b4[f]; }
        xv[j] = xvv; gv[j] = gvv; bv[j] = bvv;
        #define ACC1(v, g, b) { float g2 = (g)*(g); a[0] += (v); a[1] += (v)*(v); \
            a[2] += (v)*g2; a[3] += (v)*(v)*g2; a[4] += (v)*(g)*(b); a[5] += g2; \
            a[6] += (g)*(b); a[7] += (b)*(b); }
        ACC1(xvv.x, gvv.x, bvv.x); ACC1(xvv.y, gvv.y, bvv.y);
        ACC1(xvv.z, gvv.z, bvv.z); ACC1(xvv.w, gvv.w, bvv.w);
        #undef ACC1
    }
    #pragma unroll
    for (int m = 1; m < 64; m <<= 1) {
        #pragma unroll
        for (int t = 0; t < 8; ++t) a[t] += __shfl_xor(a[t], m);
    }
    float mu   = a[0] * (1.f / 720.f);
    float var  = a[1] * (1.f / 720.f) - mu * mu;
    float rsig = rsqrtf(var + 1e-5f);
    float ny2  = rsig * rsig * (a[3] - 2.f * mu * a[2] + mu * mu * a[5])
               + 2.f * rsig * (a[4] - mu * a[6]) + a[7];
    float rn   = 1.f / fmaxf(sqrtf(fmaxf(ny2, 0.f)), 1e-12f);
    float pp   = rsig * rn;
    float qq   = -pp * mu;
    if (lane == 0) pscale[n] = make_float4(pp, qq, rn, 0.f);

    int e8 = n & 7;
    _Float16* orow = xh + (size_t)n * CPAD;
    #pragma unroll
    for (int j = 0; j < 3; ++j) {
        int f = lane + 64 * j;                 // float4 index 0..191 (>=180 -> zeros)
        float4 xvv = xv[j], gvv = gv[j], bvv = bv[j];
        h4 o;
        o.x = (_Float16)((pp * xvv.x + qq) * gvv.x + rn * bvv.x);
        o.y = (_Float16)((pp * xvv.y + qq) * gvv.y + rn * bvv.y);
        o.z = (_Float16)((pp * xvv.z + qq) * gvv.z + rn * bvv.z);
        o.w = (_Float16)((pp * xvv.w + qq) * gvv.w + rn * bvv.w);
        int off = ((((f >> 1) ^ e8) << 3) | ((f & 1) << 2));
        *reinterpret_cast<h4*>(orow + off) = o;
    }
}

// ------------------------------------------------------------------
// f16 MFMA GEMM: pure global_load_lds staging (linear dest, source pre-swizzled),
// XOR-swizzled ds_read_b128, fused epilogue (sim write, argmax, e=exp, E/cnt).
__global__ __launch_bounds__(256) void gemm_sim(
        const _Float16* __restrict__ xh,
        const _Float16* __restrict__ pf16,
        const int*    __restrict__ gt_seg,
        float* __restrict__ out_sim,
        float* __restrict__ out_pred,
        float* __restrict__ epix,
        float* __restrict__ E,
        float* __restrict__ cnt,
        int*   __restrict__ tiecnt,
        int*   __restrict__ tielist) {
    __shared__ __align__(16) char smem[32768];
    _Float16* xs = (_Float16*)smem;            // [64][64] halves, swizzled content
    _Float16* ps = (_Float16*)(smem + 8192);   // [192][64] halves, swizzled content

    int tid = threadIdx.x;
    int wave = tid >> 6, lane = tid & 63;
    int lane15 = lane & 15, quad = lane >> 4;
    int n0 = blockIdx.x * 64;
    int rsub = lane >> 3, csub = (lane & 7) << 3;

    f32x4 acc[12];
    #pragma unroll
    for (int ct = 0; ct < 12; ++ct)
        acc[ct] = (f32x4){0.f, 0.f, 0.f, 0.f};

    #pragma unroll 1
    for (int ch = 0; ch < 12; ++ch) {
        __syncthreads();
        // stage x tile: 64 rows x 128B, linear LDS, per-lane global addr
        #pragma unroll
        for (int i = 0; i < 2; ++i) {
            int r0 = wave * 16 + i * 8;
            const _Float16* g = xh + (size_t)(n0 + r0 + rsub) * CPAD + ch * 64 + csub;
            async16(g, xs + r0 * 64);
        }
        // stage proto tile: 192 rows x 128B
        #pragma unroll
        for (int i = 0; i < 6; ++i) {
            int r0 = wave * 48 + i * 8;
            const _Float16* g = pf16 + (size_t)(r0 + rsub) * CPAD + ch * 64 + csub;
            async16(g, ps + r0 * 64);
        }
        __syncthreads();
        int e8 = lane15 & 7;
        #pragma unroll
        for (int ks = 0; ks < 2; ++ks) {
            int so = (((ks * 4 + quad) ^ e8) << 3);
            half8 a0 = *reinterpret_cast<const half8*>(xs + (wave * 16 + lane15) * 64 + so);
            half8 b[12];
            #pragma unroll
            for (int ct = 0; ct < 12; ++ct)
                b[ct] = *reinterpret_cast<const half8*>(ps + (ct * 16 + lane15) * 64 + so);
            #pragma unroll
            for (int ct = 0; ct < 12; ++ct)
                acc[ct] = __builtin_amdgcn_mfma_f32_16x16x32_f16(a0, b[ct], acc[ct], 0, 0, 0);
        }
    }

    // ---- fused epilogue ----
    __syncthreads();                    // done reading xs/ps
    float* fsm   = (float*)smem;
    float* ebuf  = fsm + wave * 1600;
    float* smaxw = fsm + 6400 + wave * 152;
    float* Eks   = fsm + 7008;
    float* hists = fsm + 7200;
    if (tid < 212) fsm[7008 + tid] = 0.f;
    __syncthreads();

    #pragma unroll
    for (int h = 0; h < 2; ++h) {
        if ((quad >> 1) == h) {
            int prow = (quad - 2 * h) * 4;      // 0 or 4
            #pragma unroll
            for (int ct = 0; ct < 12; ++ct) {
                int proto = ct * 16 + lane15;
                if (proto < NPROTO) {
                    int kc = proto / 10;
                    int m = proto - kc * 10;
                    int obase = m * 19 + kc;
                    #pragma unroll
                    for (int r = 0; r < 4; ++r)
                        ebuf[(prow + r) * 200 + obase] = acc[ct][r];
                }
            }
        }
        __syncthreads();
        #pragma unroll
        for (int p = 0; p < 8; ++p) {
            int pixel = n0 + wave * 16 + 8 * h + p;
            #pragma unroll
            for (int j = 0; j < 3; ++j) {
                int col = lane + 64 * j;
                if (col < NPROTO)
                    out_sim[(size_t)pixel * 190 + col] = ebuf[p * 200 + col];
            }
        }
        #pragma unroll
        for (int t = lane; t < 152; t += 64) {
            int p = t / 19, k = t - p * 19;
            const float* row = ebuf + p * 200;
            float mx = row[k];
            #pragma unroll
            for (int m = 1; m < 10; ++m) mx = fmaxf(mx, row[m * 19 + k]);
            smaxw[t] = mx;
        }
        __syncthreads();
        if (lane < 8) {
            int p = lane;
            int pixel = n0 + wave * 16 + 8 * h + p;
            float best = smaxw[p * 19], second = -1e30f;
            int bk = 0;
            #pragma unroll
            for (int k = 1; k < 19; ++k) {
                float v = smaxw[p * 19 + k];
                if (v > best) { second = best; best = v; bk = k; }
                else if (v > second) second = v;
            }
            out_pred[pixel] = (float)bk;
            if (best - second < 3e-4f) {
                int pos = atomicAdd(tiecnt, 1);
                if (pos < N_PIX) tielist[pos] = pixel;
            }
            int g = gt_seg[pixel];
            atomicAdd(&hists[g], 1.f);
            const float* row = ebuf + p * 200;
            #pragma unroll
            for (int m = 0; m < 10; ++m) {
                float ev = __expf(row[m * 19 + g] * 20.f);
                epix[(size_t)pixel * 10 + m] = ev;
                atomicAdd(&Eks[g * 10 + m], ev);
            }
        }
        __syncthreads();
    }
    if (tid < 190) atomicAdd(&E[tid], Eks[tid]);
    if (tid < 19)  atomicAdd(&cnt[tid], hists[tid]);
}

// ------------------------------------------------------------------
// fp64 recompute of argmax for near-tie pixels
__global__ void tiefix(const float* __restrict__ x,
                       const float4* __restrict__ pscale,
                       const float* __restrict__ gamma,
                       const float* __restrict__ beta,
                       const float* __restrict__ pf32,
                       const int* __restrict__ tiecnt,
                       const int* __restrict__ tielist,
                       float* __restrict__ out_pred) {
    __shared__ float xrow[720];
    __shared__ double sd[190];
    int count = *tiecnt;
    if (count > N_PIX) count = N_PIX;
    int wave = threadIdx.x >> 6, lane = threadIdx.x & 63;
    for (int it = blockIdx.x; it < count; it += gridDim.x) {
        int n = tielist[it];
        float4 sc = pscale[n];
        for (int c = threadIdx.x; c < 720; c += 256)
            xrow[c] = (sc.x * x[(size_t)n * 720 + c] + sc.y) * gamma[c] + sc.z * beta[c];
        __syncthreads();
        for (int p = wave; p < NPROTO; p += 4) {
            const float* pr = pf32 + (size_t)p * 720;
            double a = 0.0;
            for (int j = 0; j < 12; ++j) {
                int i = lane + 64 * j;
                if (i < 720) a += (double)xrow[i] * (double)pr[i];
            }
            #pragma unroll
            for (int m = 1; m < 64; m <<= 1) a += __shfl_xor(a, m);
            if (lane == 0) sd[p] = a;
        }
        __syncthreads();
        if (threadIdx.x == 0) {
            double best = -1e300;
            int bk = 0;
            for (int k = 0; k < 19; ++k) {
                double sk = -1e300;
                for (int m = 0; m < 10; ++m) sk = fmax(sk, sd[k * 10 + m]);
                if (sk > best) { best = sk; bk = k; }
            }
            out_pred[n] = (float)bk;
        }
        __syncthreads();
    }
}

// ------------------------------------------------------------------
// Sinkhorn row pass with in-block v recompute (fuses v1k/v23k).
// Gprev==nullptr -> v = v1(E); else v = v23(v1(E), Gprev).
__global__ void pk_fused(const float* __restrict__ epix,
                         const int* __restrict__ gt_seg,
                         const float* __restrict__ E,
                         const float* __restrict__ Gprev,
                         const float* __restrict__ cnt,
                         const float* __restrict__ uin,
                         float* __restrict__ uout,
                         float* __restrict__ Gout) {
    __shared__ float Es[190];
    __shared__ float vs[190];
    __shared__ float cs[19];
    __shared__ float Ga[190];
    int tid = threadIdx.x;
    if (tid < 190) { Es[tid] = E[tid]; Ga[tid] = 0.f; }
    if (tid < 19) cs[tid] = cnt[tid];
    __syncthreads();
    if (tid < 190) {
        int k = tid / 10;
        float S = 0.f;
        #pragma unroll
        for (int m = 0; m < 10; ++m) S += Es[k * 10 + m];
        float v0 = 1.f / fmaxf(S, 1e-12f);
        float vv = v0 / (fmaxf(v0 * Es[tid], 1e-12f) * 10.f);
        if (Gprev) vv = vv / (fmaxf(vv * Gprev[tid], 1e-12f) * 10.f);
        vs[tid] = vv;
    }
    __syncthreads();
    int n = blockIdx.x * 256 + tid;
    int g = gt_seg[n];
    float ns = fmaxf(cs[g], 1.f);
    const float* e = epix + (size_t)n * 10;
    float ev[10];
    float dot = 0.f;
    #pragma unroll
    for (int m = 0; m < 10; ++m) { ev[m] = e[m]; dot += ev[m] * vs[g * 10 + m]; }
    float up = uin ? uin[n] : 1.f;
    float c = up * dot;
    float uu = up / (fmaxf(c, 1e-12f) * ns);
    uout[n] = uu;
    #pragma unroll
    for (int m = 0; m < 10; ++m) atomicAdd(&Ga[g * 10 + m], ev[m] * uu);
    __syncthreads();
    if (tid < 190) atomicAdd(&Gout[tid], Ga[tid]);
}

// final row-normalize + q = e*u3*v3*n_safe (v3 recomputed in-block)
__global__ void p3k_fused(const float* __restrict__ epix,
                          const int* __restrict__ gt_seg,
                          const float* __restrict__ E,
                          const float* __restrict__ G2,
                          const float* __restrict__ G3,
                          const float* __restrict__ cnt,
                          const float* __restrict__ uin,
                          float* __restrict__ qout) {
    __shared__ float Es[190];
    __shared__ float vs[190];
    __shared__ float cs[19];
    int tid = threadIdx.x;
    if (tid < 190) Es[tid] = E[tid];
    if (tid < 19) cs[tid] = cnt[tid];
    __syncthreads();
    if (tid < 190) {
        int k = tid / 10;
        float S = 0.f;
        #pragma unroll
        for (int m = 0; m < 10; ++m) S += Es[k * 10 + m];
        float v0 = 1.f / fmaxf(S, 1e-12f);
        float vv = v0 / (fmaxf(v0 * Es[tid], 1e-12f) * 10.f);
        vv = vv / (fmaxf(vv * G2[tid], 1e-12f) * 10.f);
        vv = vv / (fmaxf(vv * G3[tid], 1e-12f) * 10.f);
        vs[tid] = vv;
    }
    __syncthreads();
    int n = blockIdx.x * 256 + tid;
    int g = gt_seg[n];
    float ns = fmaxf(cs[g], 1.f);
    const float* e = epix + (size_t)n * 10;
    float ev[10];
    float dot = 0.f;
    #pragma unroll
    for (int m = 0; m < 10; ++m) { ev[m] = e[m]; dot += ev[m] * vs[g * 10 + m]; }
    float up = uin[n];
    float c = up * dot;
    float u3 = up / (fmaxf(c, 1e-12f) * ns);
    float2 qv[5];
    #pragma unroll
    for (int j = 0; j < 5; ++j) {
        qv[j].x = ev[2 * j] * u3 * vs[g * 10 + 2 * j] * ns;
        qv[j].y = ev[2 * j + 1] * u3 * vs[g * 10 + 2 * j + 1] * ns;
    }
    const float2 z2 = make_float2(0.f, 0.f);
    for (int k = 0; k < 19; ++k) {
        float2* dst = reinterpret_cast<float2*>(qout + (size_t)k * 655360 + (size_t)n * 10);
        if (k == g) {
            #pragma unroll
            for (int j = 0; j < 5; ++j) dst[j] = qv[j];
        } else {
            #pragma unroll
            for (int j = 0; j < 5; ++j) dst[j] = z2;
        }
    }
}

// ------------------------------------------------------------------
extern "C" void kernel_launch(void* const* d_in, const int* in_sizes, int n_in,
                              void* d_out, int out_size, void* d_ws, size_t ws_size,
                              hipStream_t stream) {
    const float* x      = (const float*)d_in[0];
    const int*   gt     = (const int*)d_in[1];
    const float* gamma  = (const float*)d_in[2];
    const float* beta   = (const float*)d_in[3];
    const float* protos = (const float*)d_in[4];
    float* out = (float*)d_out;
    char* ws = (char*)d_ws;

    float*  E       = (float*)(ws + WS_E);
    float*  G2      = (float*)(ws + WS_G2);
    float*  G3      = (float*)(ws + WS_G3);
    float*  cnt     = (float*)(ws + WS_CNT);
    int*    tiecnt  = (int*)(ws + WS_TIECNT);
    float4* pscale  = (float4*)(ws + WS_PSCALE);
    float*  epix    = (float*)(ws + WS_EPIX);
    float*  u       = (float*)(ws + WS_U);
    int*    tielist = (int*)(ws + WS_TIELIST);
    _Float16* pf16  = (_Float16*)(ws + WS_PF16);
    float*  pf32    = (float*)(ws + WS_PF32);
    _Float16* xh    = (_Float16*)(ws + WS_XH);

    zero_acc<<<1, 1024, 0, stream>>>((float*)ws);
    proto_prep<<<192, 256, 0, stream>>>(protos, pf16, pf32);
    stats_xh<<<16384, 256, 0, stream>>>(x, gamma, beta, pscale, xh);
    gemm_sim<<<1024, 256, 0, stream>>>(xh, pf16, gt,
                                       out, out + OFF_PRED, epix, E, cnt, tiecnt, tielist);
    tiefix<<<1024, 256, 0, stream>>>(x, pscale, gamma, beta, pf32, tiecnt, tielist, out + OFF_PRED);
    pk_fused<<<256, 256, 0, stream>>>(epix, gt, E, nullptr, cnt, nullptr, u, G2);
    pk_fused<<<256, 256, 0, stream>>>(epix, gt, E, G2, cnt, u, u, G3);
    p3k_fused<<<256, 256, 0, stream>>>(epix, gt, E, G2, G3, cnt, u, out + OFF_Q);
}

// Round 3
// 491.025 us; speedup vs baseline: 1.0237x; 1.0237x over previous
//
#include <hip/hip_runtime.h>
#include <stdint.h>

#define N_PIX    65536
#define C_DIM    720
#define K_CLS    19
#define M_PROTO  10
#define NPROTO   190
#define CPAD     768
#define OFF_Q    12451840
#define OFF_PRED 24903680

typedef _Float16 half8 __attribute__((ext_vector_type(8)));
typedef _Float16 h4    __attribute__((ext_vector_type(4)));
typedef float    f32x4 __attribute__((ext_vector_type(4)));

// ---- workspace layout (byte offsets) ----
#define WS_E       0u          // 192 floats
#define WS_G2      768u        // 192 floats
#define WS_G3      1536u       // 192 floats
#define WS_CNT     2304u       // 32 floats
#define WS_TIECNT  2432u       // 1 int
#define WS_PSCALE  4096u       // 65536 * float4
#define WS_EPIX    1052672u    // 65536*10 floats
#define WS_U       3674112u    // 65536 floats
#define WS_TIELIST 3936256u    // 65536 ints
#define WS_PF16    4198400u    // 192*768 half (pre-swizzled)
#define WS_PF32    4493312u    // 190*720 float

// async 16B global->LDS copy (LDS dest wave-uniform base; HW adds lane*16)
__device__ __forceinline__ void async16(const void* g, void* l) {
    __builtin_amdgcn_global_load_lds(
        (const __attribute__((address_space(1))) unsigned int*)g,
        (__attribute__((address_space(3))) unsigned int*)l, 16, 0, 0);
}

// ------------------------------------------------------------------
// L2-normalize prototypes -> f16 padded+swizzled [192][768] and f32 [190][720].
// Block 191 (padding) also zeroes the small accumulator region (E,G2,G3,cnt,tiecnt).
__global__ void proto_prep(const float* __restrict__ protos,
                           _Float16* __restrict__ pf16,
                           float* __restrict__ pf32,
                           float* __restrict__ wsf) {
    int p = blockIdx.x;
    int tid = threadIdx.x;
    if (p >= NPROTO) {   // padding rows 190,191 -> zeros
        for (int c = tid; c < CPAD; c += 256) pf16[(size_t)p * CPAD + c] = (_Float16)0.f;
        if (p == 191) for (int i = tid; i < 640; i += 256) wsf[i] = 0.f;
        return;
    }
    __shared__ float red[256];
    const float* row = protos + (size_t)p * C_DIM;
    float ss = 0.f;
    for (int c = tid; c < C_DIM; c += 256) { float v = row[c]; ss += v * v; }
    red[tid] = ss;
    __syncthreads();
    for (int s = 128; s > 0; s >>= 1) {
        if (tid < s) red[tid] += red[tid + s];
        __syncthreads();
    }
    float invn = 1.f / fmaxf(sqrtf(red[0]), 1e-12f);
    int e8 = p & 7;
    for (int c = tid; c < CPAD; c += 256) {
        float v = (c < C_DIM) ? row[c] * invn : 0.f;
        int sw = (((c >> 3) ^ e8) << 3) | (c & 7);
        pf16[(size_t)p * CPAD + sw] = (_Float16)v;
        if (c < C_DIM) pf32[(size_t)p * C_DIM + c] = v;
    }
}

// ------------------------------------------------------------------
// Fused: LN stats (x read ONCE from HBM) -> swizzled f16 x-tile in LDS ->
// MFMA GEMM vs async-staged protos -> fused epilogue (sim, argmax/tie,
// e=exp, E/cnt accumulation). 32 pixels/block, 2048 blocks, 72KB dyn LDS.
__global__ __launch_bounds__(256) void gemm_fused(
        const float*  __restrict__ x,
        const float*  __restrict__ gamma,
        const float*  __restrict__ beta,
        const _Float16* __restrict__ pf16,
        const int*    __restrict__ gt_seg,
        float4* __restrict__ pscale,
        float* __restrict__ out_sim,
        float* __restrict__ out_pred,
        float* __restrict__ epix,
        float* __restrict__ E,
        float* __restrict__ cnt,
        int*   __restrict__ tiecnt,
        int*   __restrict__ tielist) {
    extern __shared__ __align__(16) char smem[];     // 73728 B
    _Float16* xt = (_Float16*)smem;                  // [32][768] swizzled
    _Float16* ps = (_Float16*)(smem + 49152);        // [192][64] swizzled

    int tid = threadIdx.x;
    int wave = tid >> 6, lane = tid & 63;
    int lane15 = lane & 15, quad = lane >> 4;
    int n0 = blockIdx.x * 32;
    int ph = wave & 1, qh = wave >> 1;
    int rsub = lane >> 3, csub = (lane & 7) << 3;

    // ---- phase 0: per-row LN stats + f16 conversion into LDS x-tile ----
    const float4* g4 = (const float4*)gamma;
    const float4* b4 = (const float4*)beta;
    float4 gv[3], bv[3];
    #pragma unroll
    for (int j = 0; j < 3; ++j) {
        int f = lane + 64 * j;
        float4 z = make_float4(0.f, 0.f, 0.f, 0.f);
        gv[j] = (f < 180) ? g4[f] : z;
        bv[j] = (f < 180) ? b4[f] : z;
    }
    #pragma unroll 1
    for (int rr = 0; rr < 8; ++rr) {
        int row = wave * 8 + rr;            // tile row 0..31
        int n = n0 + row;
        const float4* row4 = (const float4*)(x + (size_t)n * C_DIM);
        float a[8];
        #pragma unroll
        for (int t = 0; t < 8; ++t) a[t] = 0.f;
        float4 xv[3];
        #pragma unroll
        for (int j = 0; j < 3; ++j) {
            int f = lane + 64 * j;
            float4 z = make_float4(0.f, 0.f, 0.f, 0.f);
            float4 xvv = (f < 180) ? row4[f] : z;
            xv[j] = xvv;
            float4 gvv = gv[j], bvv = bv[j];
            #define ACC1(v, g, b) { float g2 = (g)*(g); a[0] += (v); a[1] += (v)*(v); \
                a[2] += (v)*g2; a[3] += (v)*(v)*g2; a[4] += (v)*(g)*(b); a[5] += g2; \
                a[6] += (g)*(b); a[7] += (b)*(b); }
            ACC1(xvv.x, gvv.x, bvv.x); ACC1(xvv.y, gvv.y, bvv.y);
            ACC1(xvv.z, gvv.z, bvv.z); ACC1(xvv.w, gvv.w, bvv.w);
            #undef ACC1
        }
        #pragma unroll
        for (int m = 1; m < 64; m <<= 1) {
            #pragma unroll
            for (int t = 0; t < 8; ++t) a[t] += __shfl_xor(a[t], m);
        }
        float mu   = a[0] * (1.f / 720.f);
        float var  = a[1] * (1.f / 720.f) - mu * mu;
        float rsig = rsqrtf(var + 1e-5f);
        float ny2  = rsig * rsig * (a[3] - 2.f * mu * a[2] + mu * mu * a[5])
                   + 2.f * rsig * (a[4] - mu * a[6]) + a[7];
        float rn   = 1.f / fmaxf(sqrtf(fmaxf(ny2, 0.f)), 1e-12f);
        float pp   = rsig * rn;
        float qq   = -pp * mu;
        if (lane == 0) pscale[n] = make_float4(pp, qq, rn, 0.f);
        #pragma unroll
        for (int j = 0; j < 3; ++j) {
            int f = lane + 64 * j;          // float4 index 0..191 (>=180 are zeros)
            float4 xvv = xv[j], gvv = gv[j], bvv = bv[j];
            h4 o;
            o.x = (_Float16)((pp * xvv.x + qq) * gvv.x + rn * bvv.x);
            o.y = (_Float16)((pp * xvv.y + qq) * gvv.y + rn * bvv.y);
            o.z = (_Float16)((pp * xvv.z + qq) * gvv.z + rn * bvv.z);
            o.w = (_Float16)((pp * xvv.w + qq) * gvv.w + rn * bvv.w);
            int gl = f >> 1;                              // 16B group 0..95
            int gp = (gl & 0x78) | ((gl ^ row) & 7);      // XOR swizzle within 8-group
            *reinterpret_cast<h4*>(xt + row * 768 + gp * 8 + (f & 1) * 4) = o;
        }
    }

    // ---- phase 1: MFMA over 12 K-chunks, protos staged per-chunk ----
    f32x4 acc[6];
    #pragma unroll
    for (int ct = 0; ct < 6; ++ct) acc[ct] = (f32x4){0.f, 0.f, 0.f, 0.f};

    int e8 = lane15 & 7;
    #pragma unroll 1
    for (int ch = 0; ch < 12; ++ch) {
        __syncthreads();                    // xt ready (ch=0) / ps reads done (ch>0)
        #pragma unroll
        for (int i = 0; i < 6; ++i) {
            int r0 = wave * 48 + i * 8;
            const _Float16* g = pf16 + (size_t)(r0 + rsub) * CPAD + ch * 64 + csub;
            async16(g, ps + r0 * 64);
        }
        __syncthreads();                    // vmcnt drained by barrier semantics
        #pragma unroll
        for (int ks = 0; ks < 2; ++ks) {
            int s = (ks * 4 + quad) ^ e8;
            half8 a0 = *reinterpret_cast<const half8*>(
                xt + (ph * 16 + lane15) * 768 + (ch * 8 + s) * 8);
            half8 b[6];
            #pragma unroll
            for (int ct = 0; ct < 6; ++ct)
                b[ct] = *reinterpret_cast<const half8*>(
                    ps + (qh * 96 + ct * 16 + lane15) * 64 + s * 8);
            #pragma unroll
            for (int ct = 0; ct < 6; ++ct)
                acc[ct] = __builtin_amdgcn_mfma_f32_16x16x32_f16(a0, b[ct], acc[ct], 0, 0, 0);
        }
    }

    // ---- epilogue (overlays xt region; ps untouched) ----
    __syncthreads();
    float* fsm   = (float*)smem;
    float* ebuf  = fsm;              // [32][200]
    float* smaxs = fsm + 6400;       // 608
    float* Eks   = fsm + 7008;       // 190
    float* hist  = fsm + 7200;       // 19
    if (tid < 224) fsm[7008 + tid] = 0.f;
    // scatter accs: pixel = ph*16 + quad*4 + r, proto = qh*96 + ct*16 + lane15
    #pragma unroll
    for (int ct = 0; ct < 6; ++ct) {
        int proto = qh * 96 + ct * 16 + lane15;
        if (proto < NPROTO) {
            int kc = proto / 10;
            int m = proto - kc * 10;
            int ob = m * 19 + kc;
            int prow = ph * 16 + quad * 4;
            #pragma unroll
            for (int r = 0; r < 4; ++r)
                ebuf[(prow + r) * 200 + ob] = acc[ct][r];
        }
    }
    __syncthreads();
    // coalesced sim writes
    for (int t2 = tid; t2 < 32 * 192; t2 += 256) {
        int p = t2 / 192, col = t2 - p * 192;
        if (col < NPROTO)
            out_sim[(size_t)(n0 + p) * 190 + col] = ebuf[p * 200 + col];
    }
    // per-(pixel,class) max over 10 prototypes
    for (int t2 = tid; t2 < 608; t2 += 256) {
        int p = t2 / 19, k = t2 - p * 19;
        const float* rowp = ebuf + p * 200;
        float mx = rowp[k];
        #pragma unroll
        for (int m = 1; m < 10; ++m) mx = fmaxf(mx, rowp[m * 19 + k]);
        smaxs[t2] = mx;
    }
    __syncthreads();
    if (tid < 32) {
        int p = tid;
        int pixel = n0 + p;
        float best = smaxs[p * 19], second = -1e30f;
        int bk = 0;
        #pragma unroll
        for (int k = 1; k < 19; ++k) {
            float v = smaxs[p * 19 + k];
            if (v > best) { second = best; best = v; bk = k; }
            else if (v > second) second = v;
        }
        out_pred[pixel] = (float)bk;
        if (best - second < 3e-4f) {
            int pos = atomicAdd(tiecnt, 1);
            if (pos < N_PIX) tielist[pos] = pixel;
        }
        int g = gt_seg[pixel];
        atomicAdd(&hist[g], 1.f);
        const float* rowp = ebuf + p * 200;
        #pragma unroll
        for (int m = 0; m < 10; ++m) {
            float ev = __expf(rowp[m * 19 + g] * 20.f);
            epix[(size_t)pixel * 10 + m] = ev;
            atomicAdd(&Eks[g * 10 + m], ev);
        }
    }
    __syncthreads();
    if (tid < 190) atomicAdd(&E[tid], Eks[tid]);
    if (tid < 19)  atomicAdd(&cnt[tid], hist[tid]);
}

// ------------------------------------------------------------------
// fp64 recompute of argmax for near-tie pixels
__global__ void tiefix(const float* __restrict__ x,
                       const float4* __restrict__ pscale,
                       const float* __restrict__ gamma,
                       const float* __restrict__ beta,
                       const float* __restrict__ pf32,
                       const int* __restrict__ tiecnt,
                       const int* __restrict__ tielist,
                       float* __restrict__ out_pred) {
    __shared__ float xrow[720];
    __shared__ double sd[190];
    int count = *tiecnt;
    if (count > N_PIX) count = N_PIX;
    int wave = threadIdx.x >> 6, lane = threadIdx.x & 63;
    for (int it = blockIdx.x; it < count; it += gridDim.x) {
        int n = tielist[it];
        float4 sc = pscale[n];
        for (int c = threadIdx.x; c < 720; c += 256)
            xrow[c] = (sc.x * x[(size_t)n * 720 + c] + sc.y) * gamma[c] + sc.z * beta[c];
        __syncthreads();
        for (int p = wave; p < NPROTO; p += 4) {
            const float* pr = pf32 + (size_t)p * 720;
            double a = 0.0;
            for (int j = 0; j < 12; ++j) {
                int i = lane + 64 * j;
                if (i < 720) a += (double)xrow[i] * (double)pr[i];
            }
            #pragma unroll
            for (int m = 1; m < 64; m <<= 1) a += __shfl_xor(a, m);
            if (lane == 0) sd[p] = a;
        }
        __syncthreads();
        if (threadIdx.x == 0) {
            double best = -1e300;
            int bk = 0;
            for (int k = 0; k < 19; ++k) {
                double sk = -1e300;
                for (int m = 0; m < 10; ++m) sk = fmax(sk, sd[k * 10 + m]);
                if (sk > best) { best = sk; bk = k; }
            }
            out_pred[n] = (float)bk;
        }
        __syncthreads();
    }
}

// ------------------------------------------------------------------
// Sinkhorn row pass with in-block v recompute.
__global__ void pk_fused(const float* __restrict__ epix,
                         const int* __restrict__ gt_seg,
                         const float* __restrict__ E,
                         const float* __restrict__ Gprev,
                         const float* __restrict__ cnt,
                         const float* __restrict__ uin,
                         float* __restrict__ uout,
                         float* __restrict__ Gout) {
    __shared__ float Es[190];
    __shared__ float vs[190];
    __shared__ float cs[19];
    __shared__ float Ga[190];
    int tid = threadIdx.x;
    if (tid < 190) { Es[tid] = E[tid]; Ga[tid] = 0.f; }
    if (tid < 19) cs[tid] = cnt[tid];
    __syncthreads();
    if (tid < 190) {
        int k = tid / 10;
        float S = 0.f;
        #pragma unroll
        for (int m = 0; m < 10; ++m) S += Es[k * 10 + m];
        float v0 = 1.f / fmaxf(S, 1e-12f);
        float vv = v0 / (fmaxf(v0 * Es[tid], 1e-12f) * 10.f);
        if (Gprev) vv = vv / (fmaxf(vv * Gprev[tid], 1e-12f) * 10.f);
        vs[tid] = vv;
    }
    __syncthreads();
    int n = blockIdx.x * 256 + tid;
    int g = gt_seg[n];
    float ns = fmaxf(cs[g], 1.f);
    const float* e = epix + (size_t)n * 10;
    float ev[10];
    float dot = 0.f;
    #pragma unroll
    for (int m = 0; m < 10; ++m) { ev[m] = e[m]; dot += ev[m] * vs[g * 10 + m]; }
    float up = uin ? uin[n] : 1.f;
    float c = up * dot;
    float uu = up / (fmaxf(c, 1e-12f) * ns);
    uout[n] = uu;
    #pragma unroll
    for (int m = 0; m < 10; ++m) atomicAdd(&Ga[g * 10 + m], ev[m] * uu);
    __syncthreads();
    if (tid < 190) atomicAdd(&Gout[tid], Ga[tid]);
}

// final row-normalize + q = e*u3*v3*n_safe (v3 recomputed in-block)
__global__ void p3k_fused(const float* __restrict__ epix,
                          const int* __restrict__ gt_seg,
                          const float* __restrict__ E,
                          const float* __restrict__ G2,
                          const float* __restrict__ G3,
                          const float* __restrict__ cnt,
                          const float* __restrict__ uin,
                          float* __restrict__ qout) {
    __shared__ float Es[190];
    __shared__ float vs[190];
    __shared__ float cs[19];
    int tid = threadIdx.x;
    if (tid < 190) Es[tid] = E[tid];
    if (tid < 19) cs[tid] = cnt[tid];
    __syncthreads();
    if (tid < 190) {
        int k = tid / 10;
        float S = 0.f;
        #pragma unroll
        for (int m = 0; m < 10; ++m) S += Es[k * 10 + m];
        float v0 = 1.f / fmaxf(S, 1e-12f);
        float vv = v0 / (fmaxf(v0 * Es[tid], 1e-12f) * 10.f);
        vv = vv / (fmaxf(vv * G2[tid], 1e-12f) * 10.f);
        vv = vv / (fmaxf(vv * G3[tid], 1e-12f) * 10.f);
        vs[tid] = vv;
    }
    __syncthreads();
    int n = blockIdx.x * 256 + tid;
    int g = gt_seg[n];
    float ns = fmaxf(cs[g], 1.f);
    const float* e = epix + (size_t)n * 10;
    float ev[10];
    float dot = 0.f;
    #pragma unroll
    for (int m = 0; m < 10; ++m) { ev[m] = e[m]; dot += ev[m] * vs[g * 10 + m]; }
    float up = uin[n];
    float c = up * dot;
    float u3 = up / (fmaxf(c, 1e-12f) * ns);
    float2 qv[5];
    #pragma unroll
    for (int j = 0; j < 5; ++j) {
        qv[j].x = ev[2 * j] * u3 * vs[g * 10 + 2 * j] * ns;
        qv[j].y = ev[2 * j + 1] * u3 * vs[g * 10 + 2 * j + 1] * ns;
    }
    const float2 z2 = make_float2(0.f, 0.f);
    for (int k = 0; k < 19; ++k) {
        float2* dst = reinterpret_cast<float2*>(qout + (size_t)k * 655360 + (size_t)n * 10);
        if (k == g) {
            #pragma unroll
            for (int j = 0; j < 5; ++j) dst[j] = qv[j];
        } else {
            #pragma unroll
            for (int j = 0; j < 5; ++j) dst[j] = z2;
        }
    }
}

// ------------------------------------------------------------------
extern "C" void kernel_launch(void* const* d_in, const int* in_sizes, int n_in,
                              void* d_out, int out_size, void* d_ws, size_t ws_size,
                              hipStream_t stream) {
    const float* x      = (const float*)d_in[0];
    const int*   gt     = (const int*)d_in[1];
    const float* gamma  = (const float*)d_in[2];
    const float* beta   = (const float*)d_in[3];
    const float* protos = (const float*)d_in[4];
    float* out = (float*)d_out;
    char* ws = (char*)d_ws;

    float*  E       = (float*)(ws + WS_E);
    float*  G2      = (float*)(ws + WS_G2);
    float*  G3      = (float*)(ws + WS_G3);
    float*  cnt     = (float*)(ws + WS_CNT);
    int*    tiecnt  = (int*)(ws + WS_TIECNT);
    float4* pscale  = (float4*)(ws + WS_PSCALE);
    float*  epix    = (float*)(ws + WS_EPIX);
    float*  u       = (float*)(ws + WS_U);
    int*    tielist = (int*)(ws + WS_TIELIST);
    _Float16* pf16  = (_Float16*)(ws + WS_PF16);
    float*  pf32    = (float*)(ws + WS_PF32);

    static bool attr_set = false;
    if (!attr_set) {
        hipFuncSetAttribute((const void*)gemm_fused,
                            hipFuncAttributeMaxDynamicSharedMemorySize, 73728);
        attr_set = true;
    }

    proto_prep<<<192, 256, 0, stream>>>(protos, pf16, pf32, (float*)ws);
    gemm_fused<<<2048, 256, 73728, stream>>>(x, gamma, beta, pf16, gt, pscale,
                                             out, out + OFF_PRED, epix, E, cnt,
                                             tiecnt, tielist);
    tiefix<<<1024, 256, 0, stream>>>(x, pscale, gamma, beta, pf32, tiecnt, tielist, out + OFF_PRED);
    pk_fused<<<256, 256, 0, stream>>>(epix, gt, E, nullptr, cnt, nullptr, u, G2);
    pk_fused<<<256, 256, 0, stream>>>(epix, gt, E, G2, cnt, u, u, G3);
    p3k_fused<<<256, 256, 0, stream>>>(epix, gt, E, G2, G3, cnt, u, out + OFF_Q);
}

// Round 4
// 483.082 us; speedup vs baseline: 1.0405x; 1.0164x over previous
//
#include <hip/hip_runtime.h>
#include <stdint.h>

#define N_PIX    65536
#define C_DIM    720
#define K_CLS    19
#define M_PROTO  10
#define NPROTO   190
#define CPAD     768
#define OFF_Q    12451840
#define OFF_PRED 24903680

typedef _Float16 half8 __attribute__((ext_vector_type(8)));
typedef _Float16 h4    __attribute__((ext_vector_type(4)));
typedef float    f32x4 __attribute__((ext_vector_type(4)));

// ---- workspace layout (byte offsets) ----
#define WS_E       0u          // 192 floats
#define WS_G2      768u        // 192 floats
#define WS_G3      1536u       // 192 floats
#define WS_CNT     2304u       // 32 floats
#define WS_TIECNT  2432u       // 1 int
#define WS_PSCALE  4096u       // 65536 * float4
#define WS_EPIX    1052672u    // 65536*10 floats
#define WS_U       3674112u    // 65536 floats
#define WS_TIELIST 3936256u    // 65536 ints
#define WS_PF16    4198400u    // 192*768 half (pre-swizzled)
#define WS_PF32    4493312u    // 190*720 float

// async 16B global->LDS copy (LDS dest wave-uniform base; HW adds lane*16)
__device__ __forceinline__ void async16(const void* g, void* l) {
    __builtin_amdgcn_global_load_lds(
        (const __attribute__((address_space(1))) unsigned int*)g,
        (__attribute__((address_space(3))) unsigned int*)l, 16, 0, 0);
}

// ------------------------------------------------------------------
// L2-normalize prototypes -> f16 padded+swizzled [192][768] and f32 [190][720].
// Block 191 (padding) also zeroes the small accumulator region (E,G2,G3,cnt,tiecnt).
__global__ void proto_prep(const float* __restrict__ protos,
                           _Float16* __restrict__ pf16,
                           float* __restrict__ pf32,
                           float* __restrict__ wsf) {
    int p = blockIdx.x;
    int tid = threadIdx.x;
    if (p >= NPROTO) {   // padding rows 190,191 -> zeros
        for (int c = tid; c < CPAD; c += 256) pf16[(size_t)p * CPAD + c] = (_Float16)0.f;
        if (p == 191) for (int i = tid; i < 640; i += 256) wsf[i] = 0.f;
        return;
    }
    __shared__ float red[256];
    const float* row = protos + (size_t)p * C_DIM;
    float ss = 0.f;
    for (int c = tid; c < C_DIM; c += 256) { float v = row[c]; ss += v * v; }
    red[tid] = ss;
    __syncthreads();
    for (int s = 128; s > 0; s >>= 1) {
        if (tid < s) red[tid] += red[tid + s];
        __syncthreads();
    }
    float invn = 1.f / fmaxf(sqrtf(red[0]), 1e-12f);
    int e8 = p & 7;
    for (int c = tid; c < CPAD; c += 256) {
        float v = (c < C_DIM) ? row[c] * invn : 0.f;
        int sw = (((c >> 3) ^ e8) << 3) | (c & 7);
        pf16[(size_t)p * CPAD + sw] = (_Float16)v;
        if (c < C_DIM) pf32[(size_t)p * C_DIM + c] = v;
    }
}

// ------------------------------------------------------------------
// Fused: LN stats (x read ONCE) -> swizzled f16 x-tile in LDS -> barrier-free
// per-wave MFMA K-loop (each wave stages/consumes its own 48 proto rows) ->
// fused epilogue. 32 pixels/block, 2048 blocks, 72KB dyn LDS.
__global__ __launch_bounds__(256, 2) void gemm_fused(
        const float*  __restrict__ x,
        const float*  __restrict__ gamma,
        const float*  __restrict__ beta,
        const _Float16* __restrict__ pf16,
        const int*    __restrict__ gt_seg,
        float4* __restrict__ pscale,
        float* __restrict__ out_sim,
        float* __restrict__ out_pred,
        float* __restrict__ epix,
        float* __restrict__ E,
        float* __restrict__ cnt,
        int*   __restrict__ tiecnt,
        int*   __restrict__ tielist) {
    extern __shared__ __align__(16) char smem[];     // 73728 B
    _Float16* xt = (_Float16*)smem;                  // [32][768] swizzled
    _Float16* ps = (_Float16*)(smem + 49152);        // 4 x [48][64] per-wave private

    int tid = threadIdx.x;
    int wave = tid >> 6, lane = tid & 63;
    int lane15 = lane & 15, quad = lane >> 4;
    int n0 = blockIdx.x * 32;
    int rsub = lane >> 3, csub = (lane & 7) << 3;

    // ---- phase 0: per-row LN stats + f16 conversion into LDS x-tile ----
    const float4* g4 = (const float4*)gamma;
    const float4* b4 = (const float4*)beta;
    float4 gv[3], bv[3];
    #pragma unroll
    for (int j = 0; j < 3; ++j) {
        int f = lane + 64 * j;
        float4 z = make_float4(0.f, 0.f, 0.f, 0.f);
        gv[j] = (f < 180) ? g4[f] : z;
        bv[j] = (f < 180) ? b4[f] : z;
    }
    // issue ALL x loads up front (24 float4/lane in flight)
    float4 xv[8][3];
    #pragma unroll
    for (int rr = 0; rr < 8; ++rr) {
        int row = wave * 8 + rr;
        const float4* row4 = (const float4*)(x + (size_t)(n0 + row) * C_DIM);
        #pragma unroll
        for (int j = 0; j < 3; ++j) {
            int f = lane + 64 * j;
            float4 z = make_float4(0.f, 0.f, 0.f, 0.f);
            xv[rr][j] = (f < 180) ? row4[f] : z;
        }
    }
    // 8 independent per-row stat chains (compiler interleaves for ILP)
    #pragma unroll
    for (int rr = 0; rr < 8; ++rr) {
        int row = wave * 8 + rr;
        int n = n0 + row;
        float a[8];
        #pragma unroll
        for (int t = 0; t < 8; ++t) a[t] = 0.f;
        #pragma unroll
        for (int j = 0; j < 3; ++j) {
            float4 xvv = xv[rr][j], gvv = gv[j], bvv = bv[j];
            #define ACC1(v, g, b) { float g2 = (g)*(g); a[0] += (v); a[1] += (v)*(v); \
                a[2] += (v)*g2; a[3] += (v)*(v)*g2; a[4] += (v)*(g)*(b); a[5] += g2; \
                a[6] += (g)*(b); a[7] += (b)*(b); }
            ACC1(xvv.x, gvv.x, bvv.x); ACC1(xvv.y, gvv.y, bvv.y);
            ACC1(xvv.z, gvv.z, bvv.z); ACC1(xvv.w, gvv.w, bvv.w);
            #undef ACC1
        }
        #pragma unroll
        for (int m = 1; m < 64; m <<= 1) {
            #pragma unroll
            for (int t = 0; t < 8; ++t) a[t] += __shfl_xor(a[t], m);
        }
        float mu   = a[0] * (1.f / 720.f);
        float var  = a[1] * (1.f / 720.f) - mu * mu;
        float rsig = rsqrtf(var + 1e-5f);
        float ny2  = rsig * rsig * (a[3] - 2.f * mu * a[2] + mu * mu * a[5])
                   + 2.f * rsig * (a[4] - mu * a[6]) + a[7];
        float rn   = 1.f / fmaxf(sqrtf(fmaxf(ny2, 0.f)), 1e-12f);
        float pp   = rsig * rn;
        float qq   = -pp * mu;
        if (lane == 0) pscale[n] = make_float4(pp, qq, rn, 0.f);
        #pragma unroll
        for (int j = 0; j < 3; ++j) {
            int f = lane + 64 * j;          // float4 index 0..191 (>=180 are zeros)
            float4 xvv = xv[rr][j], gvv = gv[j], bvv = bv[j];
            h4 o;
            o.x = (_Float16)((pp * xvv.x + qq) * gvv.x + rn * bvv.x);
            o.y = (_Float16)((pp * xvv.y + qq) * gvv.y + rn * bvv.y);
            o.z = (_Float16)((pp * xvv.z + qq) * gvv.z + rn * bvv.z);
            o.w = (_Float16)((pp * xvv.w + qq) * gvv.w + rn * bvv.w);
            int gl = f >> 1;                              // 16B group 0..95
            int gp = (gl & 0x78) | ((gl ^ row) & 7);      // XOR swizzle within 8-group
            *reinterpret_cast<h4*>(xt + row * 768 + gp * 8 + (f & 1) * 4) = o;
        }
    }
    __syncthreads();   // xt complete; the ONLY barrier before the epilogue

    // ---- phase 1: barrier-free per-wave K-loop ----
    // wave owns proto rows [wave*48, wave*48+48), private LDS region.
    _Float16* myps = ps + wave * (48 * 64);
    f32x4 acc[2][3];
    #pragma unroll
    for (int pt = 0; pt < 2; ++pt)
        #pragma unroll
        for (int ct = 0; ct < 3; ++ct) acc[pt][ct] = (f32x4){0.f, 0.f, 0.f, 0.f};

    int e8 = lane15 & 7;
    #pragma unroll 1
    for (int ch = 0; ch < 12; ++ch) {
        #pragma unroll
        for (int i = 0; i < 6; ++i) {
            const _Float16* g = pf16 + (size_t)(wave * 48 + i * 8 + rsub) * CPAD + ch * 64 + csub;
            async16(g, myps + i * 8 * 64);
        }
        asm volatile("s_waitcnt vmcnt(0)" ::: "memory");
        __builtin_amdgcn_sched_barrier(0);
        #pragma unroll
        for (int ks = 0; ks < 2; ++ks) {
            int s = (ks * 4 + quad) ^ e8;
            half8 a0 = *reinterpret_cast<const half8*>(xt + (lane15) * 768 + (ch * 8 + s) * 8);
            half8 a1 = *reinterpret_cast<const half8*>(xt + (16 + lane15) * 768 + (ch * 8 + s) * 8);
            half8 b[3];
            #pragma unroll
            for (int ct = 0; ct < 3; ++ct)
                b[ct] = *reinterpret_cast<const half8*>(myps + (ct * 16 + lane15) * 64 + s * 8);
            #pragma unroll
            for (int ct = 0; ct < 3; ++ct) {
                acc[0][ct] = __builtin_amdgcn_mfma_f32_16x16x32_f16(a0, b[ct], acc[0][ct], 0, 0, 0);
                acc[1][ct] = __builtin_amdgcn_mfma_f32_16x16x32_f16(a1, b[ct], acc[1][ct], 0, 0, 0);
            }
        }
        // all ds_reads of this chunk must complete before next chunk's staging
        asm volatile("s_waitcnt lgkmcnt(0)" ::: "memory");
        __builtin_amdgcn_sched_barrier(0);
    }

    // ---- epilogue (overlays xt region) ----
    __syncthreads();                 // all waves done reading xt / staging ps
    float* fsm   = (float*)smem;
    float* ebuf  = fsm;              // [32][200]
    float* smaxs = fsm + 6400;       // 608
    float* Eks   = fsm + 7008;       // 190
    float* hist  = fsm + 7200;       // 19
    if (tid < 224) fsm[7008 + tid] = 0.f;
    // scatter accs: pixel = pt*16 + quad*4 + r, proto = wave*48 + ct*16 + lane15
    #pragma unroll
    for (int pt = 0; pt < 2; ++pt) {
        #pragma unroll
        for (int ct = 0; ct < 3; ++ct) {
            int proto = wave * 48 + ct * 16 + lane15;
            if (proto < NPROTO) {
                int kc = proto / 10;
                int m = proto - kc * 10;
                int ob = m * 19 + kc;
                int prow = pt * 16 + quad * 4;
                #pragma unroll
                for (int r = 0; r < 4; ++r)
                    ebuf[(prow + r) * 200 + ob] = acc[pt][ct][r];
            }
        }
    }
    __syncthreads();
    // coalesced sim writes
    for (int t2 = tid; t2 < 32 * 192; t2 += 256) {
        int p = t2 / 192, col = t2 - p * 192;
        if (col < NPROTO)
            out_sim[(size_t)(n0 + p) * 190 + col] = ebuf[p * 200 + col];
    }
    // per-(pixel,class) max over 10 prototypes
    for (int t2 = tid; t2 < 608; t2 += 256) {
        int p = t2 / 19, k = t2 - p * 19;
        const float* rowp = ebuf + p * 200;
        float mx = rowp[k];
        #pragma unroll
        for (int m = 1; m < 10; ++m) mx = fmaxf(mx, rowp[m * 19 + k]);
        smaxs[t2] = mx;
    }
    __syncthreads();
    if (tid < 32) {
        int p = tid;
        int pixel = n0 + p;
        float best = smaxs[p * 19], second = -1e30f;
        int bk = 0;
        #pragma unroll
        for (int k = 1; k < 19; ++k) {
            float v = smaxs[p * 19 + k];
            if (v > best) { second = best; best = v; bk = k; }
            else if (v > second) second = v;
        }
        out_pred[pixel] = (float)bk;
        if (best - second < 3e-4f) {
            int pos = atomicAdd(tiecnt, 1);
            if (pos < N_PIX) tielist[pos] = pixel;
        }
        int g = gt_seg[pixel];
        atomicAdd(&hist[g], 1.f);
        const float* rowp = ebuf + p * 200;
        #pragma unroll
        for (int m = 0; m < 10; ++m) {
            float ev = __expf(rowp[m * 19 + g] * 20.f);
            epix[(size_t)pixel * 10 + m] = ev;
            atomicAdd(&Eks[g * 10 + m], ev);
        }
    }
    __syncthreads();
    if (tid < 190) atomicAdd(&E[tid], Eks[tid]);
    if (tid < 19)  atomicAdd(&cnt[tid], hist[tid]);
}

// ------------------------------------------------------------------
// fp64 recompute of argmax for near-tie pixels
__global__ void tiefix(const float* __restrict__ x,
                       const float4* __restrict__ pscale,
                       const float* __restrict__ gamma,
                       const float* __restrict__ beta,
                       const float* __restrict__ pf32,
                       const int* __restrict__ tiecnt,
                       const int* __restrict__ tielist,
                       float* __restrict__ out_pred) {
    __shared__ float xrow[720];
    __shared__ double sd[190];
    int count = *tiecnt;
    if (count > N_PIX) count = N_PIX;
    int wave = threadIdx.x >> 6, lane = threadIdx.x & 63;
    for (int it = blockIdx.x; it < count; it += gridDim.x) {
        int n = tielist[it];
        float4 sc = pscale[n];
        for (int c = threadIdx.x; c < 720; c += 256)
            xrow[c] = (sc.x * x[(size_t)n * 720 + c] + sc.y) * gamma[c] + sc.z * beta[c];
        __syncthreads();
        for (int p = wave; p < NPROTO; p += 4) {
            const float* pr = pf32 + (size_t)p * 720;
            double a = 0.0;
            for (int j = 0; j < 12; ++j) {
                int i = lane + 64 * j;
                if (i < 720) a += (double)xrow[i] * (double)pr[i];
            }
            #pragma unroll
            for (int m = 1; m < 64; m <<= 1) a += __shfl_xor(a, m);
            if (lane == 0) sd[p] = a;
        }
        __syncthreads();
        if (threadIdx.x == 0) {
            double best = -1e300;
            int bk = 0;
            for (int k = 0; k < 19; ++k) {
                double sk = -1e300;
                for (int m = 0; m < 10; ++m) sk = fmax(sk, sd[k * 10 + m]);
                if (sk > best) { best = sk; bk = k; }
            }
            out_pred[n] = (float)bk;
        }
        __syncthreads();
    }
}

// ------------------------------------------------------------------
// Sinkhorn row pass with in-block v recompute.
__global__ void pk_fused(const float* __restrict__ epix,
                         const int* __restrict__ gt_seg,
                         const float* __restrict__ E,
                         const float* __restrict__ Gprev,
                         const float* __restrict__ cnt,
                         const float* __restrict__ uin,
                         float* __restrict__ uout,
                         float* __restrict__ Gout) {
    __shared__ float Es[190];
    __shared__ float vs[190];
    __shared__ float cs[19];
    __shared__ float Ga[190];
    int tid = threadIdx.x;
    if (tid < 190) { Es[tid] = E[tid]; Ga[tid] = 0.f; }
    if (tid < 19) cs[tid] = cnt[tid];
    __syncthreads();
    if (tid < 190) {
        int k = tid / 10;
        float S = 0.f;
        #pragma unroll
        for (int m = 0; m < 10; ++m) S += Es[k * 10 + m];
        float v0 = 1.f / fmaxf(S, 1e-12f);
        float vv = v0 / (fmaxf(v0 * Es[tid], 1e-12f) * 10.f);
        if (Gprev) vv = vv / (fmaxf(vv * Gprev[tid], 1e-12f) * 10.f);
        vs[tid] = vv;
    }
    __syncthreads();
    int n = blockIdx.x * 256 + tid;
    int g = gt_seg[n];
    float ns = fmaxf(cs[g], 1.f);
    const float* e = epix + (size_t)n * 10;
    float ev[10];
    float dot = 0.f;
    #pragma unroll
    for (int m = 0; m < 10; ++m) { ev[m] = e[m]; dot += ev[m] * vs[g * 10 + m]; }
    float up = uin ? uin[n] : 1.f;
    float c = up * dot;
    float uu = up / (fmaxf(c, 1e-12f) * ns);
    uout[n] = uu;
    #pragma unroll
    for (int m = 0; m < 10; ++m) atomicAdd(&Ga[g * 10 + m], ev[m] * uu);
    __syncthreads();
    if (tid < 190) atomicAdd(&Gout[tid], Ga[tid]);
}

// final row-normalize + q = e*u3*v3*n_safe (v3 recomputed in-block)
__global__ void p3k_fused(const float* __restrict__ epix,
                          const int* __restrict__ gt_seg,
                          const float* __restrict__ E,
                          const float* __restrict__ G2,
                          const float* __restrict__ G3,
                          const float* __restrict__ cnt,
                          const float* __restrict__ uin,
                          float* __restrict__ qout) {
    __shared__ float Es[190];
    __shared__ float vs[190];
    __shared__ float cs[19];
    int tid = threadIdx.x;
    if (tid < 190) Es[tid] = E[tid];
    if (tid < 19) cs[tid] = cnt[tid];
    __syncthreads();
    if (tid < 190) {
        int k = tid / 10;
        float S = 0.f;
        #pragma unroll
        for (int m = 0; m < 10; ++m) S += Es[k * 10 + m];
        float v0 = 1.f / fmaxf(S, 1e-12f);
        float vv = v0 / (fmaxf(v0 * Es[tid], 1e-12f) * 10.f);
        vv = vv / (fmaxf(vv * G2[tid], 1e-12f) * 10.f);
        vv = vv / (fmaxf(vv * G3[tid], 1e-12f) * 10.f);
        vs[tid] = vv;
    }
    __syncthreads();
    int n = blockIdx.x * 256 + tid;
    int g = gt_seg[n];
    float ns = fmaxf(cs[g], 1.f);
    const float* e = epix + (size_t)n * 10;
    float ev[10];
    float dot = 0.f;
    #pragma unroll
    for (int m = 0; m < 10; ++m) { ev[m] = e[m]; dot += ev[m] * vs[g * 10 + m]; }
    float up = uin[n];
    float c = up * dot;
    float u3 = up / (fmaxf(c, 1e-12f) * ns);
    float2 qv[5];
    #pragma unroll
    for (int j = 0; j < 5; ++j) {
        qv[j].x = ev[2 * j] * u3 * vs[g * 10 + 2 * j] * ns;
        qv[j].y = ev[2 * j + 1] * u3 * vs[g * 10 + 2 * j + 1] * ns;
    }
    const float2 z2 = make_float2(0.f, 0.f);
    for (int k = 0; k < 19; ++k) {
        float2* dst = reinterpret_cast<float2*>(qout + (size_t)k * 655360 + (size_t)n * 10);
        if (k == g) {
            #pragma unroll
            for (int j = 0; j < 5; ++j) dst[j] = qv[j];
        } else {
            #pragma unroll
            for (int j = 0; j < 5; ++j) dst[j] = z2;
        }
    }
}

// ------------------------------------------------------------------
extern "C" void kernel_launch(void* const* d_in, const int* in_sizes, int n_in,
                              void* d_out, int out_size, void* d_ws, size_t ws_size,
                              hipStream_t stream) {
    const float* x      = (const float*)d_in[0];
    const int*   gt     = (const int*)d_in[1];
    const float* gamma  = (const float*)d_in[2];
    const float* beta   = (const float*)d_in[3];
    const float* protos = (const float*)d_in[4];
    float* out = (float*)d_out;
    char* ws = (char*)d_ws;

    float*  E       = (float*)(ws + WS_E);
    float*  G2      = (float*)(ws + WS_G2);
    float*  G3      = (float*)(ws + WS_G3);
    float*  cnt     = (float*)(ws + WS_CNT);
    int*    tiecnt  = (int*)(ws + WS_TIECNT);
    float4* pscale  = (float4*)(ws + WS_PSCALE);
    float*  epix    = (float*)(ws + WS_EPIX);
    float*  u       = (float*)(ws + WS_U);
    int*    tielist = (int*)(ws + WS_TIELIST);
    _Float16* pf16  = (_Float16*)(ws + WS_PF16);
    float*  pf32    = (float*)(ws + WS_PF32);

    static bool attr_set = false;
    if (!attr_set) {
        hipFuncSetAttribute((const void*)gemm_fused,
                            hipFuncAttributeMaxDynamicSharedMemorySize, 73728);
        attr_set = true;
    }

    proto_prep<<<192, 256, 0, stream>>>(protos, pf16, pf32, (float*)ws);
    gemm_fused<<<2048, 256, 73728, stream>>>(x, gamma, beta, pf16, gt, pscale,
                                             out, out + OFF_PRED, epix, E, cnt,
                                             tiecnt, tielist);
    tiefix<<<1024, 256, 0, stream>>>(x, pscale, gamma, beta, pf32, tiecnt, tielist, out + OFF_PRED);
    pk_fused<<<256, 256, 0, stream>>>(epix, gt, E, nullptr, cnt, nullptr, u, G2);
    pk_fused<<<256, 256, 0, stream>>>(epix, gt, E, G2, cnt, u, u, G3);
    p3k_fused<<<256, 256, 0, stream>>>(epix, gt, E, G2, G3, cnt, u, out + OFF_Q);
}

// Round 5
// 482.662 us; speedup vs baseline: 1.0414x; 1.0009x over previous
//
#include <hip/hip_runtime.h>
#include <stdint.h>

#define N_PIX    65536
#define C_DIM    720
#define K_CLS    19
#define M_PROTO  10
#define NPROTO   190
#define CPAD     768
#define OFF_Q    12451840
#define OFF_PRED 24903680

typedef _Float16 half8 __attribute__((ext_vector_type(8)));
typedef _Float16 h4    __attribute__((ext_vector_type(4)));
typedef float    f32x4 __attribute__((ext_vector_type(4)));

// ---- workspace layout (byte offsets) ----
#define WS_E       0u          // 192 floats
#define WS_G2      768u        // 192 floats
#define WS_G3      1536u       // 192 floats
#define WS_CNT     2304u       // 32 floats
#define WS_TIECNT  2432u       // 1 int
#define WS_PSCALE  4096u       // 65536 * float4
#define WS_EPIX    1052672u    // 65536*10 floats
#define WS_U       3674112u    // 65536 floats
#define WS_TIELIST 3936256u    // 65536 ints
#define WS_PF16    4198400u    // 192*768 half (row-major, NOT swizzled)
#define WS_PF32    4493312u    // 190*720 float

// ------------------------------------------------------------------
// L2-normalize prototypes -> f16 padded [192][768] (row-major) and f32 [190][720].
// Block 191 (padding) also zeroes the small accumulator region.
__global__ void proto_prep(const float* __restrict__ protos,
                           _Float16* __restrict__ pf16,
                           float* __restrict__ pf32,
                           float* __restrict__ wsf) {
    int p = blockIdx.x;
    int tid = threadIdx.x;
    if (p >= NPROTO) {   // padding rows 190,191 -> zeros
        for (int c = tid; c < CPAD; c += 256) pf16[(size_t)p * CPAD + c] = (_Float16)0.f;
        if (p == 191) for (int i = tid; i < 640; i += 256) wsf[i] = 0.f;
        return;
    }
    __shared__ float red[256];
    const float* row = protos + (size_t)p * C_DIM;
    float ss = 0.f;
    for (int c = tid; c < C_DIM; c += 256) { float v = row[c]; ss += v * v; }
    red[tid] = ss;
    __syncthreads();
    for (int s = 128; s > 0; s >>= 1) {
        if (tid < s) red[tid] += red[tid + s];
        __syncthreads();
    }
    float invn = 1.f / fmaxf(sqrtf(red[0]), 1e-12f);
    for (int c = tid; c < CPAD; c += 256) {
        float v = (c < C_DIM) ? row[c] * invn : 0.f;
        pf16[(size_t)p * CPAD + c] = (_Float16)v;
        if (c < C_DIM) pf32[(size_t)p * C_DIM + c] = v;
    }
}

// ------------------------------------------------------------------
// Fused: LN stats (x read ONCE) -> swizzled f16 x-tile in LDS -> K-loop with
// B-fragments loaded DIRECTLY from global (L2-resident pf16, no LDS staging,
// no barriers, no manual waits) -> parallel epilogue.
// 32 pixels/block, 2048 blocks, 48KB dyn LDS -> 3 blocks/CU.
__global__ __launch_bounds__(256, 3) void gemm_fused(
        const float*  __restrict__ x,
        const float*  __restrict__ gamma,
        const float*  __restrict__ beta,
        const _Float16* __restrict__ pf16,
        const int*    __restrict__ gt_seg,
        float4* __restrict__ pscale,
        float* __restrict__ out_sim,
        float* __restrict__ out_pred,
        float* __restrict__ epix,
        float* __restrict__ E,
        float* __restrict__ cnt,
        int*   __restrict__ tiecnt,
        int*   __restrict__ tielist) {
    extern __shared__ __align__(16) char smem[];     // 49152 B
    _Float16* xt = (_Float16*)smem;                  // [32][768] swizzled

    int tid = threadIdx.x;
    int wave = tid >> 6, lane = tid & 63;
    int lane15 = lane & 15, quad = lane >> 4;
    int n0 = blockIdx.x * 32;

    // ---- phase 0: per-row LN stats + f16 conversion into LDS x-tile ----
    const float4* g4 = (const float4*)gamma;
    const float4* b4 = (const float4*)beta;
    float4 gv[3], bv[3];
    #pragma unroll
    for (int j = 0; j < 3; ++j) {
        int f = lane + 64 * j;
        float4 z = make_float4(0.f, 0.f, 0.f, 0.f);
        gv[j] = (f < 180) ? g4[f] : z;
        bv[j] = (f < 180) ? b4[f] : z;
    }
    // row-invariant sums (same butterfly order as before -> bit-identical)
    float s5 = 0.f, s6 = 0.f, s7 = 0.f;
    #pragma unroll
    for (int j = 0; j < 3; ++j) {
        float4 g = gv[j], b = bv[j];
        s5 += g.x * g.x; s6 += g.x * b.x; s7 += b.x * b.x;
        s5 += g.y * g.y; s6 += g.y * b.y; s7 += b.y * b.y;
        s5 += g.z * g.z; s6 += g.z * b.z; s7 += b.z * b.z;
        s5 += g.w * g.w; s6 += g.w * b.w; s7 += b.w * b.w;
    }
    #pragma unroll
    for (int m = 1; m < 64; m <<= 1) {
        s5 += __shfl_xor(s5, m); s6 += __shfl_xor(s6, m); s7 += __shfl_xor(s7, m);
    }

    // issue all x loads up front
    float4 xv[8][3];
    #pragma unroll
    for (int rr = 0; rr < 8; ++rr) {
        int row = wave * 8 + rr;
        const float4* row4 = (const float4*)(x + (size_t)(n0 + row) * C_DIM);
        #pragma unroll
        for (int j = 0; j < 3; ++j) {
            int f = lane + 64 * j;
            float4 z = make_float4(0.f, 0.f, 0.f, 0.f);
            xv[rr][j] = (f < 180) ? row4[f] : z;
        }
    }
    #pragma unroll
    for (int rr = 0; rr < 8; ++rr) {
        int row = wave * 8 + rr;
        int n = n0 + row;
        float a0 = 0.f, a1 = 0.f, a2 = 0.f, a3 = 0.f, a4 = 0.f;
        #pragma unroll
        for (int j = 0; j < 3; ++j) {
            float4 xvv = xv[rr][j], gvv = gv[j], bvv = bv[j];
            #define ACC1(v, g, b) { float g2 = (g)*(g); a0 += (v); a1 += (v)*(v); \
                a2 += (v)*g2; a3 += (v)*(v)*g2; a4 += (v)*(g)*(b); }
            ACC1(xvv.x, gvv.x, bvv.x); ACC1(xvv.y, gvv.y, bvv.y);
            ACC1(xvv.z, gvv.z, bvv.z); ACC1(xvv.w, gvv.w, bvv.w);
            #undef ACC1
        }
        #pragma unroll
        for (int m = 1; m < 64; m <<= 1) {
            a0 += __shfl_xor(a0, m); a1 += __shfl_xor(a1, m);
            a2 += __shfl_xor(a2, m); a3 += __shfl_xor(a3, m);
            a4 += __shfl_xor(a4, m);
        }
        float mu   = a0 * (1.f / 720.f);
        float var  = a1 * (1.f / 720.f) - mu * mu;
        float rsig = rsqrtf(var + 1e-5f);
        float ny2  = rsig * rsig * (a3 - 2.f * mu * a2 + mu * mu * s5)
                   + 2.f * rsig * (a4 - mu * s6) + s7;
        float rn   = 1.f / fmaxf(sqrtf(fmaxf(ny2, 0.f)), 1e-12f);
        float pp   = rsig * rn;
        float qq   = -pp * mu;
        if (lane == 0) pscale[n] = make_float4(pp, qq, rn, 0.f);
        #pragma unroll
        for (int j = 0; j < 3; ++j) {
            int f = lane + 64 * j;          // float4 index 0..191 (>=180 are zeros)
            float4 xvv = xv[rr][j], gvv = gv[j], bvv = bv[j];
            h4 o;
            o.x = (_Float16)((pp * xvv.x + qq) * gvv.x + rn * bvv.x);
            o.y = (_Float16)((pp * xvv.y + qq) * gvv.y + rn * bvv.y);
            o.z = (_Float16)((pp * xvv.z + qq) * gvv.z + rn * bvv.z);
            o.w = (_Float16)((pp * xvv.w + qq) * gvv.w + rn * bvv.w);
            int gl = f >> 1;                              // 16B group 0..95
            int gp = (gl & 0x78) | ((gl ^ row) & 7);      // XOR swizzle within 8-group
            *reinterpret_cast<h4*>(xt + row * 768 + gp * 8 + (f & 1) * 4) = o;
        }
    }
    __syncthreads();   // xt complete

    // ---- phase 1: K-loop, B direct from global (L2), A from LDS ----
    // wave covers protos [wave*48, wave*48+48) x all 32 pixels.
    f32x4 acc[2][3];
    #pragma unroll
    for (int pt = 0; pt < 2; ++pt)
        #pragma unroll
        for (int ct = 0; ct < 3; ++ct) acc[pt][ct] = (f32x4){0.f, 0.f, 0.f, 0.f};

    int e8 = lane15 & 7;
    const _Float16* pb0 = pf16 + (size_t)(wave * 48 + lane15) * CPAD + quad * 8;
    #pragma unroll 2
    for (int ch = 0; ch < 12; ++ch) {
        half8 b[2][3];
        #pragma unroll
        for (int ks = 0; ks < 2; ++ks)
            #pragma unroll
            for (int ct = 0; ct < 3; ++ct)
                b[ks][ct] = *reinterpret_cast<const half8*>(pb0 + ct * 16 * CPAD + ch * 64 + ks * 32);
        #pragma unroll
        for (int ks = 0; ks < 2; ++ks) {
            int s = (ks * 4 + quad) ^ e8;
            half8 a0 = *reinterpret_cast<const half8*>(xt + lane15 * 768 + (ch * 8 + s) * 8);
            half8 a1 = *reinterpret_cast<const half8*>(xt + (16 + lane15) * 768 + (ch * 8 + s) * 8);
            #pragma unroll
            for (int ct = 0; ct < 3; ++ct) {
                acc[0][ct] = __builtin_amdgcn_mfma_f32_16x16x32_f16(a0, b[ks][ct], acc[0][ct], 0, 0, 0);
                acc[1][ct] = __builtin_amdgcn_mfma_f32_16x16x32_f16(a1, b[ks][ct], acc[1][ct], 0, 0, 0);
            }
        }
    }

    // ---- epilogue (overlays xt region) ----
    __syncthreads();                 // all waves done reading xt
    float* fsm   = (float*)smem;
    float* ebuf  = fsm;              // [32][200]
    float* smaxs = fsm + 6400;       // 608
    float* Eks   = fsm + 7008;       // 190
    float* hist  = fsm + 7200;       // 19 (+pad)
    int*   gts   = (int*)(fsm + 7232);   // 32
    if (tid < 224) fsm[7008 + tid] = 0.f;
    if (tid < 32) gts[tid] = gt_seg[n0 + tid];
    // scatter accs: pixel = pt*16 + quad*4 + r, proto = wave*48 + ct*16 + lane15
    #pragma unroll
    for (int pt = 0; pt < 2; ++pt) {
        #pragma unroll
        for (int ct = 0; ct < 3; ++ct) {
            int proto = wave * 48 + ct * 16 + lane15;
            if (proto < NPROTO) {
                int kc = proto / 10;
                int m = proto - kc * 10;
                int ob = m * 19 + kc;
                int prow = pt * 16 + quad * 4;
                #pragma unroll
                for (int r = 0; r < 4; ++r)
                    ebuf[(prow + r) * 200 + ob] = acc[pt][ct][r];
            }
        }
    }
    __syncthreads();
    // coalesced sim writes
    for (int t2 = tid; t2 < 32 * 192; t2 += 256) {
        int p = t2 / 192, col = t2 - p * 192;
        if (col < NPROTO)
            out_sim[(size_t)(n0 + p) * 190 + col] = ebuf[p * 200 + col];
    }
    // per-(pixel,class) max over 10 prototypes
    for (int t2 = tid; t2 < 608; t2 += 256) {
        int p = t2 / 19, k = t2 - p * 19;
        const float* rowp = ebuf + p * 200;
        float mx = rowp[k];
        #pragma unroll
        for (int m = 1; m < 10; ++m) mx = fmaxf(mx, rowp[m * 19 + k]);
        smaxs[t2] = mx;
    }
    // parallel e = exp(sim[p][m][g]*20): 320 (p,m) pairs over 256 threads
    for (int t2 = tid; t2 < 320; t2 += 256) {
        int p = t2 / 10, m = t2 - p * 10;
        int g = gts[p];
        float ev = __expf(ebuf[p * 200 + m * 19 + g] * 20.f);
        epix[(size_t)(n0 + p) * 10 + m] = ev;
        atomicAdd(&Eks[g * 10 + m], ev);
        if (m == 0) atomicAdd(&hist[g], 1.f);
    }
    __syncthreads();
    if (tid < 32) {
        int p = tid;
        int pixel = n0 + p;
        float best = smaxs[p * 19], second = -1e30f;
        int bk = 0;
        #pragma unroll
        for (int k = 1; k < 19; ++k) {
            float v = smaxs[p * 19 + k];
            if (v > best) { second = best; best = v; bk = k; }
            else if (v > second) second = v;
        }
        out_pred[pixel] = (float)bk;
        if (best - second < 3e-4f) {
            int pos = atomicAdd(tiecnt, 1);
            if (pos < N_PIX) tielist[pos] = pixel;
        }
    }
    if (tid < 190) atomicAdd(&E[tid], Eks[tid]);
    if (tid < 19)  atomicAdd(&cnt[tid], hist[tid]);
}

// ------------------------------------------------------------------
// fp64 recompute of argmax for near-tie pixels
__global__ void tiefix(const float* __restrict__ x,
                       const float4* __restrict__ pscale,
                       const float* __restrict__ gamma,
                       const float* __restrict__ beta,
                       const float* __restrict__ pf32,
                       const int* __restrict__ tiecnt,
                       const int* __restrict__ tielist,
                       float* __restrict__ out_pred) {
    __shared__ float xrow[720];
    __shared__ double sd[190];
    int count = *tiecnt;
    if (count > N_PIX) count = N_PIX;
    int wave = threadIdx.x >> 6, lane = threadIdx.x & 63;
    for (int it = blockIdx.x; it < count; it += gridDim.x) {
        int n = tielist[it];
        float4 sc = pscale[n];
        for (int c = threadIdx.x; c < 720; c += 256)
            xrow[c] = (sc.x * x[(size_t)n * 720 + c] + sc.y) * gamma[c] + sc.z * beta[c];
        __syncthreads();
        for (int p = wave; p < NPROTO; p += 4) {
            const float* pr = pf32 + (size_t)p * 720;
            double a = 0.0;
            for (int j = 0; j < 12; ++j) {
                int i = lane + 64 * j;
                if (i < 720) a += (double)xrow[i] * (double)pr[i];
            }
            #pragma unroll
            for (int m = 1; m < 64; m <<= 1) a += __shfl_xor(a, m);
            if (lane == 0) sd[p] = a;
        }
        __syncthreads();
        if (threadIdx.x == 0) {
            double best = -1e300;
            int bk = 0;
            for (int k = 0; k < 19; ++k) {
                double sk = -1e300;
                for (int m = 0; m < 10; ++m) sk = fmax(sk, sd[k * 10 + m]);
                if (sk > best) { best = sk; bk = k; }
            }
            out_pred[n] = (float)bk;
        }
        __syncthreads();
    }
}

// ------------------------------------------------------------------
// Sinkhorn row pass with in-block v recompute.
__global__ void pk_fused(const float* __restrict__ epix,
                         const int* __restrict__ gt_seg,
                         const float* __restrict__ E,
                         const float* __restrict__ Gprev,
                         const float* __restrict__ cnt,
                         const float* __restrict__ uin,
                         float* __restrict__ uout,
                         float* __restrict__ Gout) {
    __shared__ float Es[190];
    __shared__ float vs[190];
    __shared__ float cs[19];
    __shared__ float Ga[190];
    int tid = threadIdx.x;
    if (tid < 190) { Es[tid] = E[tid]; Ga[tid] = 0.f; }
    if (tid < 19) cs[tid] = cnt[tid];
    __syncthreads();
    if (tid < 190) {
        int k = tid / 10;
        float S = 0.f;
        #pragma unroll
        for (int m = 0; m < 10; ++m) S += Es[k * 10 + m];
        float v0 = 1.f / fmaxf(S, 1e-12f);
        float vv = v0 / (fmaxf(v0 * Es[tid], 1e-12f) * 10.f);
        if (Gprev) vv = vv / (fmaxf(vv * Gprev[tid], 1e-12f) * 10.f);
        vs[tid] = vv;
    }
    __syncthreads();
    int n = blockIdx.x * 256 + tid;
    int g = gt_seg[n];
    float ns = fmaxf(cs[g], 1.f);
    const float* e = epix + (size_t)n * 10;
    float ev[10];
    float dot = 0.f;
    #pragma unroll
    for (int m = 0; m < 10; ++m) { ev[m] = e[m]; dot += ev[m] * vs[g * 10 + m]; }
    float up = uin ? uin[n] : 1.f;
    float c = up * dot;
    float uu = up / (fmaxf(c, 1e-12f) * ns);
    uout[n] = uu;
    #pragma unroll
    for (int m = 0; m < 10; ++m) atomicAdd(&Ga[g * 10 + m], ev[m] * uu);
    __syncthreads();
    if (tid < 190) atomicAdd(&Gout[tid], Ga[tid]);
}

// final row-normalize + q = e*u3*v3*n_safe (v3 recomputed in-block)
__global__ void p3k_fused(const float* __restrict__ epix,
                          const int* __restrict__ gt_seg,
                          const float* __restrict__ E,
                          const float* __restrict__ G2,
                          const float* __restrict__ G3,
                          const float* __restrict__ cnt,
                          const float* __restrict__ uin,
                          float* __restrict__ qout) {
    __shared__ float Es[190];
    __shared__ float vs[190];
    __shared__ float cs[19];
    int tid = threadIdx.x;
    if (tid < 190) Es[tid] = E[tid];
    if (tid < 19) cs[tid] = cnt[tid];
    __syncthreads();
    if (tid < 190) {
        int k = tid / 10;
        float S = 0.f;
        #pragma unroll
        for (int m = 0; m < 10; ++m) S += Es[k * 10 + m];
        float v0 = 1.f / fmaxf(S, 1e-12f);
        float vv = v0 / (fmaxf(v0 * Es[tid], 1e-12f) * 10.f);
        vv = vv / (fmaxf(vv * G2[tid], 1e-12f) * 10.f);
        vv = vv / (fmaxf(vv * G3[tid], 1e-12f) * 10.f);
        vs[tid] = vv;
    }
    __syncthreads();
    int n = blockIdx.x * 256 + tid;
    int g = gt_seg[n];
    float ns = fmaxf(cs[g], 1.f);
    const float* e = epix + (size_t)n * 10;
    float ev[10];
    float dot = 0.f;
    #pragma unroll
    for (int m = 0; m < 10; ++m) { ev[m] = e[m]; dot += ev[m] * vs[g * 10 + m]; }
    float up = uin[n];
    float c = up * dot;
    float u3 = up / (fmaxf(c, 1e-12f) * ns);
    float2 qv[5];
    #pragma unroll
    for (int j = 0; j < 5; ++j) {
        qv[j].x = ev[2 * j] * u3 * vs[g * 10 + 2 * j] * ns;
        qv[j].y = ev[2 * j + 1] * u3 * vs[g * 10 + 2 * j + 1] * ns;
    }
    const float2 z2 = make_float2(0.f, 0.f);
    for (int k = 0; k < 19; ++k) {
        float2* dst = reinterpret_cast<float2*>(qout + (size_t)k * 655360 + (size_t)n * 10);
        if (k == g) {
            #pragma unroll
            for (int j = 0; j < 5; ++j) dst[j] = qv[j];
        } else {
            #pragma unroll
            for (int j = 0; j < 5; ++j) dst[j] = z2;
        }
    }
}

// ------------------------------------------------------------------
extern "C" void kernel_launch(void* const* d_in, const int* in_sizes, int n_in,
                              void* d_out, int out_size, void* d_ws, size_t ws_size,
                              hipStream_t stream) {
    const float* x      = (const float*)d_in[0];
    const int*   gt     = (const int*)d_in[1];
    const float* gamma  = (const float*)d_in[2];
    const float* beta   = (const float*)d_in[3];
    const float* protos = (const float*)d_in[4];
    float* out = (float*)d_out;
    char* ws = (char*)d_ws;

    float*  E       = (float*)(ws + WS_E);
    float*  G2      = (float*)(ws + WS_G2);
    float*  G3      = (float*)(ws + WS_G3);
    float*  cnt     = (float*)(ws + WS_CNT);
    int*    tiecnt  = (int*)(ws + WS_TIECNT);
    float4* pscale  = (float4*)(ws + WS_PSCALE);
    float*  epix    = (float*)(ws + WS_EPIX);
    float*  u       = (float*)(ws + WS_U);
    int*    tielist = (int*)(ws + WS_TIELIST);
    _Float16* pf16  = (_Float16*)(ws + WS_PF16);
    float*  pf32    = (float*)(ws + WS_PF32);

    static bool attr_set = false;
    if (!attr_set) {
        hipFuncSetAttribute((const void*)gemm_fused,
                            hipFuncAttributeMaxDynamicSharedMemorySize, 49152);
        attr_set = true;
    }

    proto_prep<<<192, 256, 0, stream>>>(protos, pf16, pf32, (float*)ws);
    gemm_fused<<<2048, 256, 49152, stream>>>(x, gamma, beta, pf16, gt, pscale,
                                             out, out + OFF_PRED, epix, E, cnt,
                                             tiecnt, tielist);
    tiefix<<<1024, 256, 0, stream>>>(x, pscale, gamma, beta, pf32, tiecnt, tielist, out + OFF_PRED);
    pk_fused<<<256, 256, 0, stream>>>(epix, gt, E, nullptr, cnt, nullptr, u, G2);
    pk_fused<<<256, 256, 0, stream>>>(epix, gt, E, G2, cnt, u, u, G3);
    p3k_fused<<<256, 256, 0, stream>>>(epix, gt, E, G2, G3, cnt, u, out + OFF_Q);
}